// Round 1
// baseline (203.282 us; speedup 1.0000x reference)
//
#include <hip/hip_runtime.h>
#include <hip/hip_bf16.h>

#define DM 512
#define NTOK 1024
#define NB 16

typedef _Float16 f16;
typedef _Float16 half8 __attribute__((ext_vector_type(8)));
typedef _Float16 half4_t __attribute__((ext_vector_type(4)));
typedef float f32x4 __attribute__((ext_vector_type(4)));

__device__ __forceinline__ void gload16(const void* g, void* l) {
    __builtin_amdgcn_global_load_lds(
        (const __attribute__((address_space(1))) void*)g,
        (__attribute__((address_space(3))) void*)l, 16, 0, 0);
}

// ---------------- transpose + convert: x f32 [B][C][N] -> xt f16 [B][N][C] ----------------
__global__ __launch_bounds__(256)
void transpose_x_kernel(const float* __restrict__ x, f16* __restrict__ xt) {
    __shared__ float tile[32][33];
    int b = blockIdx.z;
    int n0 = blockIdx.x * 32, c0 = blockIdx.y * 32;
    int tx = threadIdx.x, ty = threadIdx.y;  // 32 x 8
    const float* xb = x + (size_t)b * DM * NTOK;
#pragma unroll
    for (int i = 0; i < 32; i += 8)
        tile[ty + i][tx] = xb[(size_t)(c0 + ty + i) * NTOK + n0 + tx];
    __syncthreads();
    f16* xtb = xt + (size_t)b * NTOK * DM;
#pragma unroll
    for (int i = 0; i < 32; i += 8)
        xtb[(size_t)(n0 + ty + i) * DM + c0 + tx] = (f16)tile[tx][ty + i];
}

__global__ __launch_bounds__(256)
void convert_w_kernel(const float* __restrict__ src, f16* __restrict__ dst, int n) {
    int i = blockIdx.x * 256 + threadIdx.x;
    if (i < n) dst[i] = (f16)src[i];
}

// ---------------- NT GEMM: D[i][j] = sum_k A[i][k]*B[j][k], 128x128 tile, 4 waves ----------------
// MODE 0: f16 out = D + bias[j]
// MODE 1: f16 out = D + bias[i]
// MODE 2: f32 out = D * scale
// MODE 3: f32 out = D + bias[i] + resid[i][j]
// MODE 4: f16 out = D
template<int MODE>
__global__ __launch_bounds__(256)
void gemm_nt(const f16* __restrict__ A, const f16* __restrict__ B, void* __restrict__ Cout,
             const float* __restrict__ bias, const float* __restrict__ resid,
             int K, int ldA, int ldB, int ldC,
             long sA, long sB, long sC, long sR, float scale) {
    __shared__ f16 As[128 * 32];
    __shared__ f16 Bs[128 * 32];
    int z = blockIdx.z;
    const f16* Ab = A + (size_t)z * sA;
    const f16* Bb = B + (size_t)z * sB;
    int tid = threadIdx.x;
    int wave = tid >> 6, lane = tid & 63;
    int wr = wave >> 1, wc = wave & 1;
    int tI = blockIdx.y * 128, tJ = blockIdx.x * 128;

    f32x4 acc[4][4];
#pragma unroll
    for (int m = 0; m < 4; ++m)
#pragma unroll
        for (int n = 0; n < 4; ++n) acc[m][n] = (f32x4){0.f, 0.f, 0.f, 0.f};

    int frow = lane & 15, fk = (lane >> 4) * 8;   // fragment addressing
    int sr = lane >> 2, sc = (lane & 3) * 8;      // staging addressing

    for (int k0 = 0; k0 < K; k0 += 32) {
#pragma unroll
        for (int h = 0; h < 2; ++h) {
            int chunk = wave * 2 + h;             // 0..7, 16 rows each
            int r = chunk * 16 + sr;
            const f16* ga = Ab + (size_t)(tI + r) * ldA + k0 + sc;
            const f16* gb = Bb + (size_t)(tJ + r) * ldB + k0 + sc;
            gload16(ga, &As[chunk * 512 + lane * 8]);
            gload16(gb, &Bs[chunk * 512 + lane * 8]);
        }
        asm volatile("s_waitcnt vmcnt(0)" ::: "memory");
        __syncthreads();

        half8 af[4], bf[4];
#pragma unroll
        for (int m = 0; m < 4; ++m)
            af[m] = *(const half8*)&As[(wr * 64 + m * 16 + frow) * 32 + fk];
#pragma unroll
        for (int n = 0; n < 4; ++n)
            bf[n] = *(const half8*)&Bs[(wc * 64 + n * 16 + frow) * 32 + fk];
#pragma unroll
        for (int m = 0; m < 4; ++m)
#pragma unroll
            for (int n = 0; n < 4; ++n)
                acc[m][n] = __builtin_amdgcn_mfma_f32_16x16x32_f16(af[m], bf[n], acc[m][n], 0, 0, 0);
        __syncthreads();
    }

    // epilogue: D row = (lane>>4)*4 + r, col = lane&15  (verified m89 mapping)
    int ro = (lane >> 4) * 4, co = lane & 15;
#pragma unroll
    for (int m = 0; m < 4; ++m) {
#pragma unroll
        for (int n = 0; n < 4; ++n) {
            int gj = tJ + wc * 64 + n * 16 + co;
#pragma unroll
            for (int r = 0; r < 4; ++r) {
                int gi = tI + wr * 64 + m * 16 + ro + r;
                float v = acc[m][n][r];
                size_t off = (size_t)z * sC + (size_t)gi * ldC + gj;
                if (MODE == 0)      ((f16*)Cout)[off] = (f16)(v + bias[gj]);
                else if (MODE == 1) ((f16*)Cout)[off] = (f16)(v + bias[gi]);
                else if (MODE == 2) ((float*)Cout)[off] = v * scale;
                else if (MODE == 3) ((float*)Cout)[off] = v + bias[gi] + resid[(size_t)z * sR + (size_t)gi * ldC + gj];
                else                ((f16*)Cout)[off] = (f16)v;
            }
        }
    }
}

// ---------------- row softmax over 1024 cols; writes f32 back + f16 copy ----------------
__global__ __launch_bounds__(256)
void softmax_kernel(float* __restrict__ attn, f16* __restrict__ attn16) {
    size_t row = blockIdx.x;
    float* p = attn + row * 1024;
    int t = threadIdx.x, lane = t & 63, wave = t >> 6;
    float4 v = reinterpret_cast<float4*>(p)[t];
    float mx = fmaxf(fmaxf(v.x, v.y), fmaxf(v.z, v.w));
#pragma unroll
    for (int o = 32; o >= 1; o >>= 1) mx = fmaxf(mx, __shfl_xor(mx, o, 64));
    __shared__ float redm[4], reds[4];
    if (lane == 0) redm[wave] = mx;
    __syncthreads();
    mx = fmaxf(fmaxf(redm[0], redm[1]), fmaxf(redm[2], redm[3]));
    v.x = __expf(v.x - mx); v.y = __expf(v.y - mx);
    v.z = __expf(v.z - mx); v.w = __expf(v.w - mx);
    float s = v.x + v.y + v.z + v.w;
#pragma unroll
    for (int o = 32; o >= 1; o >>= 1) s += __shfl_xor(s, o, 64);
    if (lane == 0) reds[wave] = s;
    __syncthreads();
    s = reds[0] + reds[1] + reds[2] + reds[3];
    float inv = 1.0f / s;
    v.x *= inv; v.y *= inv; v.z *= inv; v.w *= inv;
    reinterpret_cast<float4*>(p)[t] = v;
    half4_t hv = {(f16)v.x, (f16)v.y, (f16)v.z, (f16)v.w};
    *reinterpret_cast<half4_t*>(&attn16[row * 1024 + t * 4]) = hv;
}

extern "C" void kernel_launch(void* const* d_in, const int* in_sizes, int n_in,
                              void* d_out, int out_size, void* d_ws, size_t ws_size,
                              hipStream_t stream) {
    const float* x  = (const float*)d_in[0];
    const float* Wq = (const float*)d_in[1];
    const float* bq = (const float*)d_in[2];
    const float* Wk = (const float*)d_in[3];
    const float* bk = (const float*)d_in[4];
    const float* Wv = (const float*)d_in[5];
    const float* bv = (const float*)d_in[6];
    const float* Wo = (const float*)d_in[7];
    const float* bo = (const float*)d_in[8];

    float* out0 = (float*)d_out;                           // [16][512][1024]
    float* attn = (float*)d_out + (size_t)NB * DM * NTOK;  // [16][1024][1024] f32

    // workspace layout (f16 elements). at16 aliases qh+kth (dead after scores);
    // oh aliases xt (dead after V projection). total = 34,603,008 f16 = 69.2 MB
    f16* ws   = (f16*)d_ws;
    f16* xt   = ws;                        // [B][N][C]  8,388,608
    f16* wqh  = ws + 8388608;              //            262,144
    f16* wkh  = ws + 8650752;
    f16* wvh  = ws + 8912896;
    f16* woh  = ws + 9175040;
    f16* qh   = ws + 9437184;              // [B][N][C]  8,388,608
    f16* kth  = ws + 17825792;             // [B][N][C]  8,388,608
    f16* at16 = ws + 9437184;              // [B][N][N] 16,777,216 (aliases qh,kth)
    f16* vh   = ws + 26214400;             // [B][C][N]  8,388,608
    f16* oh   = ws;                        // [B][N][C]  (aliases xt)

    const long sTok  = (long)NTOK * DM;    // 524288
    const long sAttn = (long)NTOK * NTOK;  // 1048576
    const float scal = 0.044194173824159216f;  // 1/sqrt(512)

    transpose_x_kernel<<<dim3(32, 16, NB), dim3(32, 8), 0, stream>>>(x, xt);
    convert_w_kernel<<<1024, 256, 0, stream>>>(Wq, wqh, 262144);
    convert_w_kernel<<<1024, 256, 0, stream>>>(Wk, wkh, 262144);
    convert_w_kernel<<<1024, 256, 0, stream>>>(Wv, wvh, 262144);
    convert_w_kernel<<<1024, 256, 0, stream>>>(Wo, woh, 262144);

    // Q = xt·Wq^T + bq  -> [N][512] f16 token-major
    gemm_nt<0><<<dim3(4, 8, NB), 256, 0, stream>>>(xt, wqh, qh, bq, nullptr,
        512, 512, 512, 512, sTok, 0, sTok, 0, 0.f);
    // K = xt·Wk^T + bk
    gemm_nt<0><<<dim3(4, 8, NB), 256, 0, stream>>>(xt, wkh, kth, bk, nullptr,
        512, 512, 512, 512, sTok, 0, sTok, 0, 0.f);
    // V = Wv·xt^T + bv -> [512][1024] f16 channel-major
    gemm_nt<1><<<dim3(8, 4, NB), 256, 0, stream>>>(wvh, xt, vh, bv, nullptr,
        512, 512, 512, 1024, 0, sTok, sTok, 0, 0.f);
    // scores = Q·K^T * 1/sqrt(C) -> f32 straight into d_out attention slot
    gemm_nt<2><<<dim3(8, 8, NB), 256, 0, stream>>>(qh, kth, attn, nullptr, nullptr,
        512, 512, 512, 1024, sTok, sTok, sAttn, 0, scal);
    // softmax rows in-place (f32) + f16 copy for PV
    softmax_kernel<<<NB * NTOK, 256, 0, stream>>>(attn, at16);
    // O = attn·V^T -> [N][512] token-major
    gemm_nt<4><<<dim3(4, 8, NB), 256, 0, stream>>>(at16, vh, oh, nullptr, nullptr,
        1024, 1024, 1024, 512, sAttn, sTok, sTok, 0, 0.f);
    // out0 = Wo·O^T + bo + x
    gemm_nt<3><<<dim3(8, 4, NB), 256, 0, stream>>>(woh, oh, out0, bo, x,
        512, 512, 512, 1024, 0, sTok, sTok, sTok, 0.f);
}

// Round 2
// 188.807 us; speedup vs baseline: 1.0767x; 1.0767x over previous
//
#include <hip/hip_runtime.h>
#include <hip/hip_bf16.h>

#define DM 512
#define NTOK 1024
#define NB 16

typedef _Float16 f16;
typedef _Float16 half8 __attribute__((ext_vector_type(8)));
typedef _Float16 half4_t __attribute__((ext_vector_type(4)));
typedef float f32x4 __attribute__((ext_vector_type(4)));

__device__ __forceinline__ void gload16(const void* g, void* l) {
    __builtin_amdgcn_global_load_lds(
        (const __attribute__((address_space(1))) void*)g,
        (__attribute__((address_space(3))) void*)l, 16, 0, 0);
}

// ---------------- transpose + convert: x f32 [B][C][N] -> xt f16 [B][N][C] ----------------
__global__ __launch_bounds__(256)
void transpose_x_kernel(const float* __restrict__ x, f16* __restrict__ xt) {
    __shared__ float tile[32][33];
    int b = blockIdx.z;
    int n0 = blockIdx.x * 32, c0 = blockIdx.y * 32;
    int tx = threadIdx.x, ty = threadIdx.y;  // 32 x 8
    const float* xb = x + (size_t)b * DM * NTOK;
#pragma unroll
    for (int i = 0; i < 32; i += 8)
        tile[ty + i][tx] = xb[(size_t)(c0 + ty + i) * NTOK + n0 + tx];
    __syncthreads();
    f16* xtb = xt + (size_t)b * NTOK * DM;
#pragma unroll
    for (int i = 0; i < 32; i += 8)
        xtb[(size_t)(n0 + ty + i) * DM + c0 + tx] = (f16)tile[tx][ty + i];
}

// concat-convert Wq,Wk,Wv -> wqkvh [1536][512] f16
__global__ __launch_bounds__(256)
void convert_wqkv_kernel(const float* __restrict__ Wq, const float* __restrict__ Wk,
                         const float* __restrict__ Wv, f16* __restrict__ dst) {
    int i = blockIdx.x * 256 + threadIdx.x;  // 0..786431
    int row = i >> 9, col = i & 511;
    float v = (row < 512) ? Wq[i] : (row < 1024) ? Wk[(row - 512) * 512 + col]
                                                 : Wv[(row - 1024) * 512 + col];
    dst[i] = (f16)v;
}

__global__ __launch_bounds__(256)
void convert_w_kernel(const float* __restrict__ src, f16* __restrict__ dst, int n) {
    int i = blockIdx.x * 256 + threadIdx.x;
    if (i < n) dst[i] = (f16)src[i];
}

__global__ __launch_bounds__(256)
void concat_bias_kernel(const float* __restrict__ bq, const float* __restrict__ bk,
                        const float* __restrict__ bv, float* __restrict__ dst) {
    int i = blockIdx.x * 256 + threadIdx.x;  // 0..1535
    dst[i] = (i < 512) ? bq[i] : (i < 1024) ? bk[i - 512] : bv[i - 1024];
}

// V slice of qkv [B][N][1536] (cols 1024..1535) -> vh [B][512][1024] channel-major
__global__ __launch_bounds__(256)
void transpose_v_kernel(const f16* __restrict__ qkv, f16* __restrict__ vh) {
    __shared__ f16 tile[32][34];
    int b = blockIdx.z;
    int n0 = blockIdx.x * 32, c0 = blockIdx.y * 32;
    int tx = threadIdx.x, ty = threadIdx.y;  // 32 x 8
    const f16* src = qkv + (size_t)b * NTOK * 1536 + 1024;
#pragma unroll
    for (int i = 0; i < 32; i += 8)
        tile[ty + i][tx] = src[(size_t)(n0 + ty + i) * 1536 + c0 + tx];  // tile[n][c]
    __syncthreads();
    f16* dst = vh + (size_t)b * DM * NTOK;
#pragma unroll
    for (int i = 0; i < 32; i += 8)
        dst[(size_t)(c0 + ty + i) * NTOK + n0 + tx] = tile[tx][ty + i];
}

// ---------------- NT GEMM: D[i][j] = sum_k A[i][k]*B[j][k], 128x128 tile, 4 waves ----------------
// MODE 0: f16 out = D + bias[j]
// MODE 2: f32 out = D * scale
// MODE 3: f32 out = D + bias[i] + resid[i][j]
// MODE 4: f16 out = D
template<int MODE, int KC>
__global__ __launch_bounds__(256)
void gemm_nt(const f16* __restrict__ A, const f16* __restrict__ B, void* __restrict__ Cout,
             const float* __restrict__ bias, const float* __restrict__ resid,
             int ldA, int ldB, int ldC,
             long sA, long sB, long sC, long sR, float scale) {
    __shared__ f16 As[128 * 32];
    __shared__ f16 Bs[128 * 32];
    int z = blockIdx.z;
    const f16* Ab = A + (size_t)z * sA;
    const f16* Bb = B + (size_t)z * sB;
    int tid = threadIdx.x;
    int wave = tid >> 6, lane = tid & 63;
    int wr = wave >> 1, wc = wave & 1;
    int tI = blockIdx.y * 128, tJ = blockIdx.x * 128;

    f32x4 acc[4][4];
#pragma unroll
    for (int m = 0; m < 4; ++m)
#pragma unroll
        for (int n = 0; n < 4; ++n) acc[m][n] = (f32x4){0.f, 0.f, 0.f, 0.f};

    int frow = lane & 15, fk = (lane >> 4) * 8;   // fragment addressing
    int sr = lane >> 2, sc = (lane & 3) * 8;      // staging addressing

    for (int k0 = 0; k0 < KC; k0 += 32) {
#pragma unroll
        for (int h = 0; h < 2; ++h) {
            int chunk = wave * 2 + h;             // 0..7, 16 rows each
            int r = chunk * 16 + sr;
            const f16* ga = Ab + (size_t)(tI + r) * ldA + k0 + sc;
            const f16* gb = Bb + (size_t)(tJ + r) * ldB + k0 + sc;
            gload16(ga, &As[chunk * 512 + lane * 8]);
            gload16(gb, &Bs[chunk * 512 + lane * 8]);
        }
        asm volatile("s_waitcnt vmcnt(0)" ::: "memory");
        __syncthreads();

        half8 af[4], bf[4];
#pragma unroll
        for (int m = 0; m < 4; ++m)
            af[m] = *(const half8*)&As[(wr * 64 + m * 16 + frow) * 32 + fk];
#pragma unroll
        for (int n = 0; n < 4; ++n)
            bf[n] = *(const half8*)&Bs[(wc * 64 + n * 16 + frow) * 32 + fk];
#pragma unroll
        for (int m = 0; m < 4; ++m)
#pragma unroll
            for (int n = 0; n < 4; ++n)
                acc[m][n] = __builtin_amdgcn_mfma_f32_16x16x32_f16(af[m], bf[n], acc[m][n], 0, 0, 0);
        __syncthreads();
    }

    // epilogue: D row = (lane>>4)*4 + r, col = lane&15  (verified m89 mapping)
    int ro = (lane >> 4) * 4, co = lane & 15;
#pragma unroll
    for (int m = 0; m < 4; ++m) {
#pragma unroll
        for (int n = 0; n < 4; ++n) {
            int gj = tJ + wc * 64 + n * 16 + co;
#pragma unroll
            for (int r = 0; r < 4; ++r) {
                int gi = tI + wr * 64 + m * 16 + ro + r;
                float v = acc[m][n][r];
                size_t off = (size_t)z * sC + (size_t)gi * ldC + gj;
                if (MODE == 0)      ((f16*)Cout)[off] = (f16)(v + bias[gj]);
                else if (MODE == 2) ((float*)Cout)[off] = v * scale;
                else if (MODE == 3) ((float*)Cout)[off] = v + bias[gi] + resid[(size_t)z * sR + (size_t)gi * ldC + gj];
                else                ((f16*)Cout)[off] = (f16)v;
            }
        }
    }
}

// ---------------- row softmax over 1024 cols; writes f32 back + f16 copy ----------------
__global__ __launch_bounds__(256)
void softmax_kernel(float* __restrict__ attn, f16* __restrict__ attn16) {
    size_t row = blockIdx.x;
    float* p = attn + row * 1024;
    int t = threadIdx.x, lane = t & 63, wave = t >> 6;
    float4 v = reinterpret_cast<float4*>(p)[t];
    float mx = fmaxf(fmaxf(v.x, v.y), fmaxf(v.z, v.w));
#pragma unroll
    for (int o = 32; o >= 1; o >>= 1) mx = fmaxf(mx, __shfl_xor(mx, o, 64));
    __shared__ float redm[4], reds[4];
    if (lane == 0) redm[wave] = mx;
    __syncthreads();
    mx = fmaxf(fmaxf(redm[0], redm[1]), fmaxf(redm[2], redm[3]));
    v.x = __expf(v.x - mx); v.y = __expf(v.y - mx);
    v.z = __expf(v.z - mx); v.w = __expf(v.w - mx);
    float s = v.x + v.y + v.z + v.w;
#pragma unroll
    for (int o = 32; o >= 1; o >>= 1) s += __shfl_xor(s, o, 64);
    if (lane == 0) reds[wave] = s;
    __syncthreads();
    s = reds[0] + reds[1] + reds[2] + reds[3];
    float inv = 1.0f / s;
    v.x *= inv; v.y *= inv; v.z *= inv; v.w *= inv;
    reinterpret_cast<float4*>(p)[t] = v;
    half4_t hv = {(f16)v.x, (f16)v.y, (f16)v.z, (f16)v.w};
    *reinterpret_cast<half4_t*>(&attn16[row * 1024 + t * 4]) = hv;
}

extern "C" void kernel_launch(void* const* d_in, const int* in_sizes, int n_in,
                              void* d_out, int out_size, void* d_ws, size_t ws_size,
                              hipStream_t stream) {
    const float* x  = (const float*)d_in[0];
    const float* Wq = (const float*)d_in[1];
    const float* bq = (const float*)d_in[2];
    const float* Wk = (const float*)d_in[3];
    const float* bk = (const float*)d_in[4];
    const float* Wv = (const float*)d_in[5];
    const float* bv = (const float*)d_in[6];
    const float* Wo = (const float*)d_in[7];
    const float* bo = (const float*)d_in[8];

    float* out0 = (float*)d_out;                           // [16][512][1024]
    float* attn = (float*)d_out + (size_t)NB * DM * NTOK;  // [16][1024][1024] f32

    // workspace layout (f16 units), peak 34,343,936 f16 = 68.7 MB (< round-1's 69.2)
    f16* ws    = (f16*)d_ws;
    f16* xt    = ws;                       // [B][N][512]   8,388,608 (vh aliases after QKV GEMM)
    f16* vh    = ws;                       // [B][512][N]   alias of xt
    f16* wqkvh = ws + 8388608;             // [1536][512]     786,432 (woh aliases after QKV GEMM)
    f16* woh   = ws + 8388608;             // [512][512]    alias of wqkvh
    float* bqkv = (float*)(ws + 9175040);  // [1536] f32       (3,072 f16 units)
    f16* qkv   = ws + 9178112;             // [B][N][1536] 25,165,824
    f16* oh    = ws + 9178112;             // [B][N][512]   alias of qkv[0..8.4M] (dead after scores)
    f16* at16  = ws + 17566720;            // [B][N][N]     alias of qkv[8.4M..25.2M]

    const long sTok  = (long)NTOK * DM;     // 524288
    const long sQkv  = (long)NTOK * 1536;   // 1572864
    const long sAttn = (long)NTOK * NTOK;   // 1048576
    const float scal = 0.044194173824159216f;  // 1/sqrt(512)

    transpose_x_kernel<<<dim3(32, 16, NB), dim3(32, 8), 0, stream>>>(x, xt);
    convert_wqkv_kernel<<<3072, 256, 0, stream>>>(Wq, Wk, Wv, wqkvh);
    concat_bias_kernel<<<6, 256, 0, stream>>>(bq, bk, bv, bqkv);

    // fused QKV = xt·Wqkv^T + bqkv -> [B][N][1536] f16 token-major
    gemm_nt<0, 512><<<dim3(12, 8, NB), 256, 0, stream>>>(xt, wqkvh, qkv, bqkv, nullptr,
        512, 512, 1536, sTok, 0, sQkv, 0, 0.f);

    // Wo convert AFTER QKV GEMM (woh aliases wqkvh)
    convert_w_kernel<<<1024, 256, 0, stream>>>(Wo, woh, 262144);
    // V slice -> channel-major vh (vh aliases xt, dead after QKV GEMM)
    transpose_v_kernel<<<dim3(32, 16, NB), dim3(32, 8), 0, stream>>>(qkv, vh);

    // scores = Q·K^T * 1/sqrt(C) -> f32 straight into d_out attention slot
    gemm_nt<2, 512><<<dim3(8, 8, NB), 256, 0, stream>>>(qkv, qkv + 512, attn, nullptr, nullptr,
        1536, 1536, 1024, sQkv, sQkv, sAttn, 0, scal);
    // softmax rows in-place (f32) + f16 copy for PV (at16 aliases dead q/k region)
    softmax_kernel<<<NB * NTOK, 256, 0, stream>>>(attn, at16);
    // O = attn·V^T -> [N][512] token-major (oh aliases dead qkv region)
    gemm_nt<4, 1024><<<dim3(4, 8, NB), 256, 0, stream>>>(at16, vh, oh, nullptr, nullptr,
        1024, 1024, 512, sAttn, sTok, sTok, 0, 0.f);
    // out0 = Wo·O^T + bo + x
    gemm_nt<3, 512><<<dim3(8, 4, NB), 256, 0, stream>>>(woh, oh, out0, bo, x,
        512, 512, 1024, 0, sTok, sTok, sTok, 0.f);
}